// Round 20
// baseline (107.453 us; speedup 1.0000x reference)
//
#include <hip/hip_runtime.h>
#include <math.h>

#define N_CELLS 4096
#define M_GENES 8192

typedef __attribute__((ext_vector_type(8))) short short8;
typedef __attribute__((ext_vector_type(4))) float f32x4;

// per-row additive terms: a_u1[4096], a_v1[8192], a_u2[4096], a_v2[8192]
__device__ __align__(16) float g_a[24576];

// bf16 copies feeding pair MFMA (g_bu: w_prod folded; g_bv: plain)
__device__ __align__(16) short g_bu1[N_CELLS * 128];
__device__ __align__(16) short g_bv1[M_GENES * 128];
__device__ __align__(16) short g_bu2[N_CELLS * 128];
__device__ __align__(16) short g_bv2[M_GENES * 128];

// transposed bf16 weights: BT[ncol][k]
__device__ __align__(16) short g_gaT[256 * 512];       // gene_act^T
__device__ __align__(16) short g_W1T[256 * 256];       // Wrna1^T
__device__ __align__(16) short g_W2T[128 * 256];       // Wrna2^T
// bf16 u inputs zero-padded K=100->128, and WbT [128 cols][128 k] padded
__device__ __align__(16) short g_ub1[N_CELLS * 128];
__device__ __align__(16) short g_ub2[N_CELLS * 128];
__device__ __align__(16) short g_WbT1[128 * 128];
__device__ __align__(16) short g_WbT2[128 * 128];

// IMPORTANT (round-3/4 lesson): device globals are NEVER passed as kernel
// arguments from host code (host-side name = shadow symbol, not device
// address -> GPU memory fault/abort). Access via device-side names only.

__device__ __forceinline__ short* bf_sel(int s) {
    switch (s) {
        case 0:  return g_bu1;
        case 1:  return g_bv1;
        case 2:  return g_bu2;
        default: return g_bv2;
    }
}

__device__ __forceinline__ const short* wt_sel(int s) {
    switch (s) {
        case 0:  return g_gaT;
        case 1:  return g_W1T;
        default: return g_W2T;
    }
}

__device__ __forceinline__ short f2bf(float f) {  // RNE fp32 -> bf16
    unsigned u = __builtin_bit_cast(unsigned, f);
    u += 0x7FFFu + ((u >> 16) & 1u);
    return (short)(u >> 16);
}

__device__ __forceinline__ void cvt8(const float* __restrict__ in, short* __restrict__ out) {
    const float4 x0 = *reinterpret_cast<const float4*>(in);
    const float4 x1 = *reinterpret_cast<const float4*>(in + 4);
    short8 o;
    o[0] = f2bf(x0.x); o[1] = f2bf(x0.y); o[2] = f2bf(x0.z); o[3] = f2bf(x0.w);
    o[4] = f2bf(x1.x); o[5] = f2bf(x1.y); o[6] = f2bf(x1.z); o[7] = f2bf(x1.w);
    *reinterpret_cast<short8*>(out) = o;
}

// out[ncol][k0..k0+7] = bf16(in[k][ncol]) for in [K][Nc] row-major
__device__ __forceinline__ void transpose8(const float* __restrict__ in, short* __restrict__ out,
                                           int c, int K, int Nc) {
    const int o0 = c * 8;
    const int ncol = o0 / K;
    const int k0 = o0 % K;
    short8 o;
#pragma unroll
    for (int j = 0; j < 8; ++j) o[j] = f2bf(in[(size_t)(k0 + j) * Nc + ncol]);
    *reinterpret_cast<short8*>(out + o0) = o;
}

// ---------------------------------------------------------------------------
// LDS staging helpers. All tiles XOR-swizzled: byte ^= ((row&7)<<4).
// ---------------------------------------------------------------------------
__device__ __forceinline__ void stage_A_f32(char* cA, const float* Af, int row0, int k0, int K, int t)
{
    const float* gAf = Af + (size_t)row0 * K + k0;
#pragma unroll
    for (int c = 0; c < 4; ++c) {
        const int idx = c * 256 + t;                // 16B chunk, 0..1023
        const int row = idx >> 4, sub = idx & 15;
        const int dst = row * 256 + ((sub * 16) ^ ((row & 7) << 4));
        cvt8(gAf + (size_t)row * K + sub * 8, (short*)(cA + dst));
    }
}

__device__ __forceinline__ void stage_B128(char* cB, const short* BT, int col0, int k0, int K, int t)
{
    const char* gB = (const char*)(BT + (size_t)col0 * K + k0);
#pragma unroll
    for (int c = 0; c < 8; ++c) {
        const int idx = c * 256 + t;                // 16B chunk, 0..2047
        const int row = idx >> 4, sub = idx & 15;
        const int dst = row * 256 + ((sub * 16) ^ ((row & 7) << 4));
        *(short8*)(cB + dst) = *(const short8*)(gB + (size_t)row * (2 * K) + sub * 16);
    }
}

__device__ __forceinline__ void stage_B64(char* cB, const short* BT, int col0, int k0, int K, int t)
{
    const char* gB = (const char*)(BT + (size_t)col0 * K + k0);
#pragma unroll
    for (int c = 0; c < 4; ++c) {
        const int idx = c * 256 + t;                // 16B chunk, 0..1023
        const int row = idx >> 4, sub = idx & 15;
        const int dst = row * 256 + ((sub * 16) ^ ((row & 7) << 4));
        *(short8*)(cB + dst) = *(const short8*)(gB + (size_t)row * (2 * K) + sub * 16);
    }
}

// ---------------------------------------------------------------------------
// MFMA helpers
// ---------------------------------------------------------------------------
__device__ __forceinline__ void mfma128(const char* cA, int strideA, int baseA,
                                        const char* cB, f32x4 (&acc)[2][4], int t)
{
    const int l = t & 63, w = t >> 6;
    const int wm = (w >> 1) * 32, wn = (w & 1) * 64;
    const int lr = l & 15, lkb = (l >> 4) * 16;
#pragma unroll
    for (int kk = 0; kk < 4; ++kk) {
        const int kb = kk * 64 + lkb;
        short8 a[2], b4[4];
#pragma unroll
        for (int i = 0; i < 2; ++i) {
            const int rA = wm + i * 16 + lr;
            a[i] = *(const short8*)(cA + rA * strideA + ((baseA + kb) ^ ((rA & 7) << 4)));
        }
#pragma unroll
        for (int jj = 0; jj < 4; ++jj) {
            const int rB = wn + jj * 16 + lr;
            b4[jj] = *(const short8*)(cB + rB * 256 + (kb ^ ((rB & 7) << 4)));
        }
#pragma unroll
        for (int i = 0; i < 2; ++i)
#pragma unroll
            for (int jj = 0; jj < 4; ++jj)
                acc[i][jj] = __builtin_amdgcn_mfma_f32_16x16x32_bf16(a[i], b4[jj], acc[i][jj], 0, 0, 0);
    }
}

__device__ __forceinline__ void mfma64(const char* cA, int strideA, int baseA,
                                       const char* cB, f32x4 (&acc)[4], int t)
{
    const int l = t & 63, w = t >> 6;
    const int wm = w * 16;
    const int lr = l & 15, lkb = (l >> 4) * 16;
#pragma unroll
    for (int kk = 0; kk < 4; ++kk) {
        const int kb = kk * 64 + lkb;
        const int rA = wm + lr;
        const short8 a = *(const short8*)(cA + rA * strideA + ((baseA + kb) ^ ((rA & 7) << 4)));
#pragma unroll
        for (int jj = 0; jj < 4; ++jj) {
            const int rB = jj * 16 + lr;
            const short8 b = *(const short8*)(cB + rB * 256 + (kb ^ ((rB & 7) << 4)));
            acc[jj] = __builtin_amdgcn_mfma_f32_16x16x32_bf16(a, b, acc[jj], 0, 0, 0);
        }
    }
}

__device__ __forceinline__ void acc_to_sH(char* sH, const f32x4 (&acc)[2][4], int ct, bool relu, int t)
{
    const int l = t & 63, w = t >> 6;
    const int wm = (w >> 1) * 32, wn = (w & 1) * 64;
    const int lr = l & 15, r4 = (l >> 4) * 4;
#pragma unroll
    for (int i = 0; i < 2; ++i)
#pragma unroll
        for (int r = 0; r < 4; ++r) {
            const int row = wm + i * 16 + r4 + r;
#pragma unroll
            for (int jj = 0; jj < 4; ++jj) {
                float x = acc[i][jj][r];
                if (relu) x = fmaxf(x, 0.f);
                const int col = ct * 128 + wn + jj * 16 + lr;
                *(short*)(sH + row * 512 + ((col * 2) ^ ((row & 7) << 4))) = f2bf(x);
            }
        }
}

__device__ __forceinline__ void acc2_to_sH(char* sH, const f32x4 (&a4)[4], int ct, bool relu, int t)
{
    const int l = t & 63, w = t >> 6;
    const int lr = l & 15, r4 = (l >> 4) * 4;
#pragma unroll
    for (int r = 0; r < 4; ++r) {
        const int row = w * 16 + r4 + r;
#pragma unroll
        for (int jj = 0; jj < 4; ++jj) {
            float x = a4[jj][r];
            if (relu) x = fmaxf(x, 0.f);
            const int col = ct * 64 + jj * 16 + lr;
            *(short*)(sH + row * 512 + ((col * 2) ^ ((row & 7) << 4))) = f2bf(x);
        }
    }
}

// ---------------------------------------------------------------------------
// MLP layers (per 64-row slab, all hidden state stays in LDS)
// ---------------------------------------------------------------------------
__device__ __forceinline__ void first_layer(const float* Vf, int row0, int KV, int bsel, bool relu,
                                            char* cA, char* cH, int t)
{
    const short* BT = wt_sel(bsel);
    f32x4 accA[2][4] = {}, accB[2][4] = {};
    for (int k0 = 0; k0 < KV; k0 += 128) {
        stage_A_f32(cA, Vf, row0, k0, KV, t);
        stage_B128(cH, BT, 0, k0, KV, t);
        __syncthreads();
        mfma128(cA, 256, 0, cH, accA, t);
        __syncthreads();
        stage_B128(cH, BT, 128, k0, KV, t);
        __syncthreads();
        mfma128(cA, 256, 0, cH, accB, t);
        __syncthreads();
    }
    acc_to_sH(cH, accA, 0, relu, t);
    acc_to_sH(cH, accB, 1, relu, t);
    __syncthreads();
}

__device__ __forceinline__ void mid_layer(char* cH, char* cB64, int t)
{
    const short* W1T = wt_sel(1);
    f32x4 h4[4][4];
#pragma unroll
    for (int ct = 0; ct < 4; ++ct)
#pragma unroll
        for (int jj = 0; jj < 4; ++jj) h4[ct][jj] = (f32x4){0.f, 0.f, 0.f, 0.f};
#pragma unroll
    for (int ct = 0; ct < 4; ++ct)
        for (int k0 = 0; k0 < 2; ++k0) {
            stage_B64(cB64, W1T, ct * 64, k0 * 128, 256, t);
            __syncthreads();
            mfma64(cH, 512, k0 * 256, cB64, h4[ct], t);
            __syncthreads();
        }
#pragma unroll
    for (int ct = 0; ct < 4; ++ct) acc2_to_sH(cH, h4[ct], ct, true, t);
    __syncthreads();
}

__device__ __forceinline__ void final_layer(char* cH, char* cB64, float* evout, short* bv,
                                            const float* w_add_hi, int a_ofs, int row0, int t)
{
    const short* W2T = wt_sel(2);
    const int l = t & 63, w = t >> 6, lr = l & 15, r4 = (l >> 4) * 4;
    float part[4] = {0.f, 0.f, 0.f, 0.f};
#pragma unroll
    for (int ct = 0; ct < 2; ++ct) {
        f32x4 a2[4] = {};
        for (int k0 = 0; k0 < 2; ++k0) {
            stage_B64(cB64, W2T, ct * 64, k0 * 128, 256, t);
            __syncthreads();
            mfma64(cH, 512, k0 * 256, cB64, a2, t);
            __syncthreads();
        }
#pragma unroll
        for (int r = 0; r < 4; ++r) {
            const int grow = row0 + w * 16 + r4 + r;
#pragma unroll
            for (int jj = 0; jj < 4; ++jj) {
                const float x = a2[jj][r];
                const int col = ct * 64 + jj * 16 + lr;
                evout[(size_t)grow * 128 + col] = x;
                bv[(size_t)grow * 128 + col] = f2bf(x);
                part[r] = fmaf(x, w_add_hi[col], part[r]);
            }
        }
    }
#pragma unroll
    for (int off = 1; off < 16; off <<= 1)
#pragma unroll
        for (int r = 0; r < 4; ++r) part[r] += __shfl_xor(part[r], off, 64);
    if (lr == 0) {
#pragma unroll
        for (int r = 0; r < 4; ++r) g_a[a_ofs + row0 + w * 16 + r4 + r] = part[r];
    }
}

// ---------------------------------------------------------------------------
// embed via MFMA
// ---------------------------------------------------------------------------
__device__ __forceinline__ void embed_mfma(int eb, const float* wp1, const float* wa1,
                                           const float* wp2, const float* wa2,
                                           float* eu1, float* eu2,
                                           char* cA, char* cB64, char* cH, int t)
{
    const int which = eb >> 6;
    const int row0 = (eb & 63) * 64;
    const short* Au  = which ? g_ub2  : g_ub1;
    const short* WbT = which ? g_WbT2 : g_WbT1;
    const float* wp = which ? wp2 : wp1;
    const float* wa = which ? wa2 : wa1;
    float* eu = which ? eu2 : eu1;
    short* bu = bf_sel(which ? 2 : 0);
    const int a_ofs = which ? 12288 : 0;

    stage_B64(cA, Au, row0, 0, 128, t);       // A tile [64][128] bf16
    stage_B128(cH, WbT, 0, 0, 128, t);        // B tile [128][128] bf16
    __syncthreads();
    f32x4 acc[2][4] = {};
    mfma128(cA, 256, 0, cH, acc, t);
    __syncthreads();

    const int l = t & 63, w = t >> 6;
    const int wm = (w >> 1) * 32, wn = (w & 1) * 64;
    const int lr = l & 15, r4 = (l >> 4) * 4;
    float* sRow = (float*)cB64;
    float wvp[4], wva[4];
#pragma unroll
    for (int jj = 0; jj < 4; ++jj) {
        const int col = wn + jj * 16 + lr;
        wvp[jj] = wp[col];
        wva[jj] = wa[col];
    }
    float part[2][4] = {};
#pragma unroll
    for (int i = 0; i < 2; ++i)
#pragma unroll
        for (int r = 0; r < 4; ++r) {
            const int grow = row0 + wm + i * 16 + r4 + r;
#pragma unroll
            for (int jj = 0; jj < 4; ++jj) {
                const float x = acc[i][jj][r];
                const int col = wn + jj * 16 + lr;
                eu[(size_t)grow * 128 + col] = x;
                bu[(size_t)grow * 128 + col] = f2bf(x * wvp[jj]);
                part[i][r] = fmaf(x, wva[jj], part[i][r]);
            }
        }
#pragma unroll
    for (int off = 1; off < 16; off <<= 1)
#pragma unroll
        for (int i = 0; i < 2; ++i)
#pragma unroll
            for (int r = 0; r < 4; ++r)
                part[i][r] += __shfl_xor(part[i][r], off, 64);
    if (t < 64) sRow[t] = 0.f;
    __syncthreads();
    if (lr == 0) {
#pragma unroll
        for (int i = 0; i < 2; ++i)
#pragma unroll
            for (int r = 0; r < 4; ++r)
                atomicAdd(&sRow[wm + i * 16 + r4 + r], part[i][r]);
    }
    __syncthreads();
    if (t < 64) g_a[a_ofs + row0 + t] = sRow[t];
}

// ---------------------------------------------------------------------------
// pair tile 64x64, 4 waves (256 threads)
// ---------------------------------------------------------------------------
__device__ __forceinline__ void pair_tile64(int which, int bb, char* cA, char* cB,
                                            const float* bias1, const float* bias2,
                                            float* out1, float* out2, int t)
{
    const int l = t & 63;
    const int col0 = (bb & 127) * 64;
    const int row0 = (bb >> 7) * 64;
    {
        const short8* gA = reinterpret_cast<const short8*>(bf_sel(which ? 2 : 0)) + (size_t)row0 * 16;
        const short8* gB = reinterpret_cast<const short8*>(bf_sel(which ? 3 : 1)) + (size_t)col0 * 16;
#pragma unroll
        for (int c = 0; c < 4; ++c) {
            const int idx = c * 256 + t;          // 16B chunk, 0..1023
            const int row = idx >> 4, sub = idx & 15;
            const int dst = row * 256 + ((sub * 16) ^ ((row & 7) << 4));
            const short8 va = gA[idx];
            const short8 vb = gB[idx];
            *(short8*)(cA + dst) = va;
            *(short8*)(cB + dst) = vb;
        }
    }
    __syncthreads();

    const int w  = t >> 6;
    const int wm = (w & 1) * 32;                  // row half
    const int wn = (w >> 1) * 32;                 // col half
    const int lr = l & 15;
    const int lkb = (l >> 4) * 16;

    f32x4 acc[2][2] = {};
#pragma unroll
    for (int kk = 0; kk < 4; ++kk) {
        const int kb = kk * 64 + lkb;
        short8 a[2], b2[2];
#pragma unroll
        for (int i = 0; i < 2; ++i) {
            const int rA = wm + i * 16 + lr;
            a[i] = *(const short8*)(cA + rA * 256 + (kb ^ ((rA & 7) << 4)));
            const int rB = wn + i * 16 + lr;
            b2[i] = *(const short8*)(cB + rB * 256 + (kb ^ ((rB & 7) << 4)));
        }
#pragma unroll
        for (int i = 0; i < 2; ++i)
#pragma unroll
            for (int j = 0; j < 2; ++j)
                acc[i][j] = __builtin_amdgcn_mfma_f32_16x16x32_bf16(a[i], b2[j], acc[i][j], 0, 0, 0);
    }

    const float bias = which ? *bias2 : *bias1;
    float* outp = which ? out2 : out1;
    const int ofsU = which ? 12288 : 0;
    const int ofsV = which ? 16384 : 4096;
    const int r4 = (l >> 4) * 4;
    float au[2][4];
#pragma unroll
    for (int i = 0; i < 2; ++i)
#pragma unroll
        for (int r = 0; r < 4; ++r)
            au[i][r] = g_a[ofsU + row0 + wm + i * 16 + r4 + r];
    float av[2];
#pragma unroll
    for (int j = 0; j < 2; ++j)
        av[j] = g_a[ofsV + col0 + wn + j * 16 + lr];

#pragma unroll
    for (int i = 0; i < 2; ++i) {
#pragma unroll
        for (int r = 0; r < 4; ++r) {
            const int grow = row0 + wm + i * 16 + r4 + r;
            float* orow = outp + (size_t)grow * M_GENES + col0 + wn;
#pragma unroll
            for (int j = 0; j < 2; ++j) {
                float x = acc[i][j][r] + au[i][r] + av[j] + bias;
                if (which == 0) x = fmaxf(x, 0.f);
                else            x = __builtin_amdgcn_rcpf(1.f + __expf(-x));
                __builtin_nontemporal_store(x, orow + j * 16 + lr);
            }
        }
    }
}

// ---------------------------------------------------------------------------
// kernels
// ---------------------------------------------------------------------------
// blocks: [0,64) gaT | [64,96) W1T | [96,112) W2T | [112,368) ub1 |
//         [368,624) ub2 | [624,632) WbT1 | [632,640) WbT2
__global__ __launch_bounds__(256) void prep_all2(const float* __restrict__ gene_act,
                                                 const float* __restrict__ W1,
                                                 const float* __restrict__ W2,
                                                 const float* __restrict__ u1,
                                                 const float* __restrict__ u2,
                                                 const float* __restrict__ Wb1,
                                                 const float* __restrict__ Wb2)
{
    const int b = blockIdx.x, t = threadIdx.x;
    if (b < 64)       transpose8(gene_act, g_gaT, b * 256 + t, 512, 256);
    else if (b < 96)  transpose8(W1, g_W1T, (b - 64) * 256 + t, 256, 256);
    else if (b < 112) transpose8(W2, g_W2T, (b - 96) * 256 + t, 256, 128);
    else if (b < 624) {
        const int which = (b >= 368);
        const int c = (b - (which ? 368 : 112)) * 256 + t;   // 0..65535
        const float* u = which ? u2 : u1;
        short* ub = which ? g_ub2 : g_ub1;
        const int row = c >> 4, sub = c & 15;
        short8 o = {0, 0, 0, 0, 0, 0, 0, 0};
        if (sub < 12) {
            const float4 x0 = *(const float4*)(u + row * 100 + sub * 8);
            const float4 x1 = *(const float4*)(u + row * 100 + sub * 8 + 4);
            o[0] = f2bf(x0.x); o[1] = f2bf(x0.y); o[2] = f2bf(x0.z); o[3] = f2bf(x0.w);
            o[4] = f2bf(x1.x); o[5] = f2bf(x1.y); o[6] = f2bf(x1.z); o[7] = f2bf(x1.w);
        } else if (sub == 12) {
            const float4 x0 = *(const float4*)(u + row * 100 + 96);
            o[0] = f2bf(x0.x); o[1] = f2bf(x0.y); o[2] = f2bf(x0.z); o[3] = f2bf(x0.w);
        }
        *(short8*)(ub + (size_t)c * 8) = o;
    } else {
        const int which = (b >= 632);
        const int c = (b - (which ? 632 : 624)) * 256 + t;   // 0..2047
        const float* Wb = which ? Wb2 : Wb1;
        short* wt = which ? g_WbT2 : g_WbT1;
        const int col = c >> 4, k0 = (c & 15) * 8;
        short8 o;
#pragma unroll
        for (int j = 0; j < 8; ++j)
            o[j] = (k0 + j < 100) ? f2bf(Wb[(size_t)(k0 + j) * 128 + col]) : (short)0;
        *(short8*)(wt + (size_t)c * 8) = o;
    }
}

// L2: blocks [0,128): stream1 MLP | [128,256): embed MFMA (both streams)
__global__ __launch_bounds__(256) void fused_s1(const float* __restrict__ v1,
                                                const float* __restrict__ wp1,
                                                const float* __restrict__ wa1,
                                                const float* __restrict__ wp2,
                                                const float* __restrict__ wa2,
                                                float* __restrict__ eu1,
                                                float* __restrict__ eu2,
                                                float* __restrict__ ev1)
{
    __shared__ __align__(16) short sMem[32768];   // 64 KB
    char* cA   = (char*)sMem;
    char* cB64 = cA + 16384;
    char* cH   = cA + 32768;
    const int b = blockIdx.x, t = threadIdx.x;
    if (b < 128) {                     // stream 1: ev1 = relu(v1@W1)@W2
        const int row0 = b * 64;
        first_layer(v1, row0, 256, 1, true, cA, cH, t);
        final_layer(cH, cB64, ev1, bf_sel(1), wa1 + 128, 4096, row0, t);
    } else {
        embed_mfma(b - 128, wp1, wa1, wp2, wa2, eu1, eu2, cA, cB64, cH, t);
    }
}

// L3: blocks [0,128): stream2 MLP | [128,6272): pair1 tiles 0..6143 -> out1
__global__ __launch_bounds__(256) void pair1_s2(const float* __restrict__ v2,
                                                const float* __restrict__ wa2,
                                                float* __restrict__ ev2,
                                                const float* __restrict__ bias1,
                                                const float* __restrict__ bias2,
                                                float* __restrict__ out1,
                                                float* __restrict__ out2)
{
    __shared__ __align__(16) short sMem[32768];   // 64 KB (MLP needs it)
    char* cA   = (char*)sMem;
    char* cB64 = cA + 16384;
    char* cH   = cA + 32768;
    const int b = blockIdx.x, t = threadIdx.x;
    if (b < 128) {                     // stream 2: ev2 = relu((v2@ga)@W1)@W2
        const int row0 = b * 64;
        first_layer(v2, row0, 512, 0, false, cA, cH, t);
        mid_layer(cH, cB64, t);
        final_layer(cH, cB64, ev2, bf_sel(3), wa2 + 128, 16384, row0, t);
    } else {
        pair_tile64(0, b - 128, cA, cA + 16384, bias1, bias2, out1, out2, t);
    }
}

// L4: remaining pair1 tiles (6144..8191) + all pair2 tiles, 32 KB LDS,
// 5 blocks/CU. XCD-chunked swizzle: each XCD gets a contiguous 1280-tile
// chunk (= its own row-panel region) so the 8 XCDs write to disjoint ~20 MB
// regions instead of interleaving 256 B segments of the same rows.
__global__ __launch_bounds__(256) void pair_rest(const float* __restrict__ bias1,
                                                 const float* __restrict__ bias2,
                                                 float* __restrict__ out1,
                                                 float* __restrict__ out2)
{
    __shared__ __align__(16) short sMem[16384];   // 32 KB
    const int b = blockIdx.x;
    const int bs = (b & 7) * 1280 + (b >> 3);     // 10240 = 8 * 1280, bijective
    if (bs < 2048)
        pair_tile64(0, bs + 6144, (char*)sMem, (char*)sMem + 16384, bias1, bias2,
                    out1, out2, threadIdx.x);
    else
        pair_tile64(1, bs - 2048, (char*)sMem, (char*)sMem + 16384, bias1, bias2,
                    out1, out2, threadIdx.x);
}

// ---------------------------------------------------------------------------
extern "C" void kernel_launch(void* const* d_in, const int* in_sizes, int n_in,
                              void* d_out, int out_size, void* d_ws, size_t ws_size,
                              hipStream_t stream)
{
    const float* u1       = (const float*)d_in[0];   // [4096,100]
    const float* u2       = (const float*)d_in[1];   // [4096,100]
    const float* v1       = (const float*)d_in[2];   // [8192,256]
    const float* v2       = (const float*)d_in[3];   // [8192,512]
    const float* Wb1      = (const float*)d_in[4];   // [100,128]
    const float* Wb2      = (const float*)d_in[5];   // [100,128]
    const float* Wrna1    = (const float*)d_in[6];   // [256,256]
    const float* Wrna2    = (const float*)d_in[7];   // [256,128]
    const float* gene_act = (const float*)d_in[8];   // [512,256]
    const float* w_prod1  = (const float*)d_in[9];   // [128]
    const float* w_add1   = (const float*)d_in[10];  // [256]
    const float* w_prod2  = (const float*)d_in[11];  // [128]
    const float* w_add2   = (const float*)d_in[12];  // [256]
    const float* bias1    = (const float*)d_in[13];  // scalar
    const float* bias2    = (const float*)d_in[14];  // scalar

    float* out  = (float*)d_out;
    float* out1 = out;                                      // [4096,8192]
    float* out2 = out1 + (size_t)N_CELLS * M_GENES;         // [4096,8192]
    float* eu1  = out2 + (size_t)N_CELLS * M_GENES;         // [4096,128]
    float* ev1  = eu1 + N_CELLS * 128;                      // [8192,128]
    float* eu2  = ev1 + M_GENES * 128;                      // [4096,128]
    float* ev2  = eu2 + N_CELLS * 128;                      // [8192,128]

    // L1: transposed bf16 weights + padded bf16 u inputs + WbT
    prep_all2<<<640, 256, 0, stream>>>(gene_act, Wrna1, Wrna2, u1, u2, Wb1, Wb2);

    // L2: stream-1 MLP + both u-embeds (everything pair1 needs)
    fused_s1<<<256, 256, 0, stream>>>(v1, w_prod1, w_add1, w_prod2, w_add2,
                                      eu1, eu2, ev1);

    // L3: stream-2 MLP + first 6144 pair1 tiles (covers the s2 window)
    pair1_s2<<<6272, 256, 0, stream>>>(v2, w_add2, ev2, bias1, bias2, out1, out2);

    // L4: remaining 2048 pair1 + all 8192 pair2 tiles, XCD-chunked order
    pair_rest<<<10240, 256, 0, stream>>>(bias1, bias2, out1, out2);
}

// Round 21
// 101.966 us; speedup vs baseline: 1.0538x; 1.0538x over previous
//
#include <hip/hip_runtime.h>
#include <math.h>

#define N_CELLS 4096
#define M_GENES 8192

typedef __attribute__((ext_vector_type(8))) short short8;
typedef __attribute__((ext_vector_type(4))) float f32x4;

// per-row additive terms: a_u1[4096], a_v1[8192], a_u2[4096], a_v2[8192]
__device__ __align__(16) float g_a[24576];

// bf16 copies feeding pair MFMA (g_bu: w_prod folded; g_bv: plain)
__device__ __align__(16) short g_bu1[N_CELLS * 128];
__device__ __align__(16) short g_bv1[M_GENES * 128];
__device__ __align__(16) short g_bu2[N_CELLS * 128];
__device__ __align__(16) short g_bv2[M_GENES * 128];

// transposed bf16 weights: BT[ncol][k]
__device__ __align__(16) short g_gaT[256 * 512];       // gene_act^T
__device__ __align__(16) short g_W1T[256 * 256];       // Wrna1^T
__device__ __align__(16) short g_W2T[128 * 256];       // Wrna2^T
// bf16 u inputs zero-padded K=100->128, and WbT [128 cols][128 k] padded
__device__ __align__(16) short g_ub1[N_CELLS * 128];
__device__ __align__(16) short g_ub2[N_CELLS * 128];
__device__ __align__(16) short g_WbT1[128 * 128];
__device__ __align__(16) short g_WbT2[128 * 128];

// IMPORTANT (round-3/4 lesson): device globals are NEVER passed as kernel
// arguments from host code (host-side name = shadow symbol, not device
// address -> GPU memory fault/abort). Access via device-side names only.

__device__ __forceinline__ short* bf_sel(int s) {
    switch (s) {
        case 0:  return g_bu1;
        case 1:  return g_bv1;
        case 2:  return g_bu2;
        default: return g_bv2;
    }
}

__device__ __forceinline__ const short* wt_sel(int s) {
    switch (s) {
        case 0:  return g_gaT;
        case 1:  return g_W1T;
        default: return g_W2T;
    }
}

__device__ __forceinline__ short f2bf(float f) {  // RNE fp32 -> bf16
    unsigned u = __builtin_bit_cast(unsigned, f);
    u += 0x7FFFu + ((u >> 16) & 1u);
    return (short)(u >> 16);
}

__device__ __forceinline__ void cvt8(const float* __restrict__ in, short* __restrict__ out) {
    const float4 x0 = *reinterpret_cast<const float4*>(in);
    const float4 x1 = *reinterpret_cast<const float4*>(in + 4);
    short8 o;
    o[0] = f2bf(x0.x); o[1] = f2bf(x0.y); o[2] = f2bf(x0.z); o[3] = f2bf(x0.w);
    o[4] = f2bf(x1.x); o[5] = f2bf(x1.y); o[6] = f2bf(x1.z); o[7] = f2bf(x1.w);
    *reinterpret_cast<short8*>(out) = o;
}

// out[ncol][k0..k0+7] = bf16(in[k][ncol]) for in [K][Nc] row-major
__device__ __forceinline__ void transpose8(const float* __restrict__ in, short* __restrict__ out,
                                           int c, int K, int Nc) {
    const int o0 = c * 8;
    const int ncol = o0 / K;
    const int k0 = o0 % K;
    short8 o;
#pragma unroll
    for (int j = 0; j < 8; ++j) o[j] = f2bf(in[(size_t)(k0 + j) * Nc + ncol]);
    *reinterpret_cast<short8*>(out + o0) = o;
}

// ---------------------------------------------------------------------------
// LDS staging helpers. All tiles XOR-swizzled: byte ^= ((row&7)<<4).
// ---------------------------------------------------------------------------
__device__ __forceinline__ void stage_A_f32(char* cA, const float* Af, int row0, int k0, int K, int t)
{
    const float* gAf = Af + (size_t)row0 * K + k0;
#pragma unroll
    for (int c = 0; c < 4; ++c) {
        const int idx = c * 256 + t;                // 16B chunk, 0..1023
        const int row = idx >> 4, sub = idx & 15;
        const int dst = row * 256 + ((sub * 16) ^ ((row & 7) << 4));
        cvt8(gAf + (size_t)row * K + sub * 8, (short*)(cA + dst));
    }
}

__device__ __forceinline__ void stage_B128(char* cB, const short* BT, int col0, int k0, int K, int t)
{
    const char* gB = (const char*)(BT + (size_t)col0 * K + k0);
#pragma unroll
    for (int c = 0; c < 8; ++c) {
        const int idx = c * 256 + t;                // 16B chunk, 0..2047
        const int row = idx >> 4, sub = idx & 15;
        const int dst = row * 256 + ((sub * 16) ^ ((row & 7) << 4));
        *(short8*)(cB + dst) = *(const short8*)(gB + (size_t)row * (2 * K) + sub * 16);
    }
}

__device__ __forceinline__ void stage_B64(char* cB, const short* BT, int col0, int k0, int K, int t)
{
    const char* gB = (const char*)(BT + (size_t)col0 * K + k0);
#pragma unroll
    for (int c = 0; c < 4; ++c) {
        const int idx = c * 256 + t;                // 16B chunk, 0..1023
        const int row = idx >> 4, sub = idx & 15;
        const int dst = row * 256 + ((sub * 16) ^ ((row & 7) << 4));
        *(short8*)(cB + dst) = *(const short8*)(gB + (size_t)row * (2 * K) + sub * 16);
    }
}

// ---------------------------------------------------------------------------
// MFMA helpers
// ---------------------------------------------------------------------------
__device__ __forceinline__ void mfma128(const char* cA, int strideA, int baseA,
                                        const char* cB, f32x4 (&acc)[2][4], int t)
{
    const int l = t & 63, w = t >> 6;
    const int wm = (w >> 1) * 32, wn = (w & 1) * 64;
    const int lr = l & 15, lkb = (l >> 4) * 16;
#pragma unroll
    for (int kk = 0; kk < 4; ++kk) {
        const int kb = kk * 64 + lkb;
        short8 a[2], b4[4];
#pragma unroll
        for (int i = 0; i < 2; ++i) {
            const int rA = wm + i * 16 + lr;
            a[i] = *(const short8*)(cA + rA * strideA + ((baseA + kb) ^ ((rA & 7) << 4)));
        }
#pragma unroll
        for (int jj = 0; jj < 4; ++jj) {
            const int rB = wn + jj * 16 + lr;
            b4[jj] = *(const short8*)(cB + rB * 256 + (kb ^ ((rB & 7) << 4)));
        }
#pragma unroll
        for (int i = 0; i < 2; ++i)
#pragma unroll
            for (int jj = 0; jj < 4; ++jj)
                acc[i][jj] = __builtin_amdgcn_mfma_f32_16x16x32_bf16(a[i], b4[jj], acc[i][jj], 0, 0, 0);
    }
}

__device__ __forceinline__ void mfma64(const char* cA, int strideA, int baseA,
                                       const char* cB, f32x4 (&acc)[4], int t)
{
    const int l = t & 63, w = t >> 6;
    const int wm = w * 16;
    const int lr = l & 15, lkb = (l >> 4) * 16;
#pragma unroll
    for (int kk = 0; kk < 4; ++kk) {
        const int kb = kk * 64 + lkb;
        const int rA = wm + lr;
        const short8 a = *(const short8*)(cA + rA * strideA + ((baseA + kb) ^ ((rA & 7) << 4)));
#pragma unroll
        for (int jj = 0; jj < 4; ++jj) {
            const int rB = jj * 16 + lr;
            const short8 b = *(const short8*)(cB + rB * 256 + (kb ^ ((rB & 7) << 4)));
            acc[jj] = __builtin_amdgcn_mfma_f32_16x16x32_bf16(a, b, acc[jj], 0, 0, 0);
        }
    }
}

__device__ __forceinline__ void acc_to_sH(char* sH, const f32x4 (&acc)[2][4], int ct, bool relu, int t)
{
    const int l = t & 63, w = t >> 6;
    const int wm = (w >> 1) * 32, wn = (w & 1) * 64;
    const int lr = l & 15, r4 = (l >> 4) * 4;
#pragma unroll
    for (int i = 0; i < 2; ++i)
#pragma unroll
        for (int r = 0; r < 4; ++r) {
            const int row = wm + i * 16 + r4 + r;
#pragma unroll
            for (int jj = 0; jj < 4; ++jj) {
                float x = acc[i][jj][r];
                if (relu) x = fmaxf(x, 0.f);
                const int col = ct * 128 + wn + jj * 16 + lr;
                *(short*)(sH + row * 512 + ((col * 2) ^ ((row & 7) << 4))) = f2bf(x);
            }
        }
}

__device__ __forceinline__ void acc2_to_sH(char* sH, const f32x4 (&a4)[4], int ct, bool relu, int t)
{
    const int l = t & 63, w = t >> 6;
    const int lr = l & 15, r4 = (l >> 4) * 4;
#pragma unroll
    for (int r = 0; r < 4; ++r) {
        const int row = w * 16 + r4 + r;
#pragma unroll
        for (int jj = 0; jj < 4; ++jj) {
            float x = a4[jj][r];
            if (relu) x = fmaxf(x, 0.f);
            const int col = ct * 64 + jj * 16 + lr;
            *(short*)(sH + row * 512 + ((col * 2) ^ ((row & 7) << 4))) = f2bf(x);
        }
    }
}

// ---------------------------------------------------------------------------
// MLP layers (per 64-row slab, all hidden state stays in LDS)
// ---------------------------------------------------------------------------
__device__ __forceinline__ void first_layer(const float* Vf, int row0, int KV, int bsel, bool relu,
                                            char* cA, char* cH, int t)
{
    const short* BT = wt_sel(bsel);
    f32x4 accA[2][4] = {}, accB[2][4] = {};
    for (int k0 = 0; k0 < KV; k0 += 128) {
        stage_A_f32(cA, Vf, row0, k0, KV, t);
        stage_B128(cH, BT, 0, k0, KV, t);
        __syncthreads();
        mfma128(cA, 256, 0, cH, accA, t);
        __syncthreads();
        stage_B128(cH, BT, 128, k0, KV, t);
        __syncthreads();
        mfma128(cA, 256, 0, cH, accB, t);
        __syncthreads();
    }
    acc_to_sH(cH, accA, 0, relu, t);
    acc_to_sH(cH, accB, 1, relu, t);
    __syncthreads();
}

__device__ __forceinline__ void mid_layer(char* cH, char* cB64, int t)
{
    const short* W1T = wt_sel(1);
    f32x4 h4[4][4];
#pragma unroll
    for (int ct = 0; ct < 4; ++ct)
#pragma unroll
        for (int jj = 0; jj < 4; ++jj) h4[ct][jj] = (f32x4){0.f, 0.f, 0.f, 0.f};
#pragma unroll
    for (int ct = 0; ct < 4; ++ct)
        for (int k0 = 0; k0 < 2; ++k0) {
            stage_B64(cB64, W1T, ct * 64, k0 * 128, 256, t);
            __syncthreads();
            mfma64(cH, 512, k0 * 256, cB64, h4[ct], t);
            __syncthreads();
        }
#pragma unroll
    for (int ct = 0; ct < 4; ++ct) acc2_to_sH(cH, h4[ct], ct, true, t);
    __syncthreads();
}

__device__ __forceinline__ void final_layer(char* cH, char* cB64, float* evout, short* bv,
                                            const float* w_add_hi, int a_ofs, int row0, int t)
{
    const short* W2T = wt_sel(2);
    const int l = t & 63, w = t >> 6, lr = l & 15, r4 = (l >> 4) * 4;
    float part[4] = {0.f, 0.f, 0.f, 0.f};
#pragma unroll
    for (int ct = 0; ct < 2; ++ct) {
        f32x4 a2[4] = {};
        for (int k0 = 0; k0 < 2; ++k0) {
            stage_B64(cB64, W2T, ct * 64, k0 * 128, 256, t);
            __syncthreads();
            mfma64(cH, 512, k0 * 256, cB64, a2, t);
            __syncthreads();
        }
#pragma unroll
        for (int r = 0; r < 4; ++r) {
            const int grow = row0 + w * 16 + r4 + r;
#pragma unroll
            for (int jj = 0; jj < 4; ++jj) {
                const float x = a2[jj][r];
                const int col = ct * 64 + jj * 16 + lr;
                evout[(size_t)grow * 128 + col] = x;
                bv[(size_t)grow * 128 + col] = f2bf(x);
                part[r] = fmaf(x, w_add_hi[col], part[r]);
            }
        }
    }
#pragma unroll
    for (int off = 1; off < 16; off <<= 1)
#pragma unroll
        for (int r = 0; r < 4; ++r) part[r] += __shfl_xor(part[r], off, 64);
    if (lr == 0) {
#pragma unroll
        for (int r = 0; r < 4; ++r) g_a[a_ofs + row0 + w * 16 + r4 + r] = part[r];
    }
}

// ---------------------------------------------------------------------------
// embed via MFMA
// ---------------------------------------------------------------------------
__device__ __forceinline__ void embed_mfma(int eb, const float* wp1, const float* wa1,
                                           const float* wp2, const float* wa2,
                                           float* eu1, float* eu2,
                                           char* cA, char* cB64, char* cH, int t)
{
    const int which = eb >> 6;
    const int row0 = (eb & 63) * 64;
    const short* Au  = which ? g_ub2  : g_ub1;
    const short* WbT = which ? g_WbT2 : g_WbT1;
    const float* wp = which ? wp2 : wp1;
    const float* wa = which ? wa2 : wa1;
    float* eu = which ? eu2 : eu1;
    short* bu = bf_sel(which ? 2 : 0);
    const int a_ofs = which ? 12288 : 0;

    stage_B64(cA, Au, row0, 0, 128, t);       // A tile [64][128] bf16
    stage_B128(cH, WbT, 0, 0, 128, t);        // B tile [128][128] bf16
    __syncthreads();
    f32x4 acc[2][4] = {};
    mfma128(cA, 256, 0, cH, acc, t);
    __syncthreads();

    const int l = t & 63, w = t >> 6;
    const int wm = (w >> 1) * 32, wn = (w & 1) * 64;
    const int lr = l & 15, r4 = (l >> 4) * 4;
    float* sRow = (float*)cB64;
    float wvp[4], wva[4];
#pragma unroll
    for (int jj = 0; jj < 4; ++jj) {
        const int col = wn + jj * 16 + lr;
        wvp[jj] = wp[col];
        wva[jj] = wa[col];
    }
    float part[2][4] = {};
#pragma unroll
    for (int i = 0; i < 2; ++i)
#pragma unroll
        for (int r = 0; r < 4; ++r) {
            const int grow = row0 + wm + i * 16 + r4 + r;
#pragma unroll
            for (int jj = 0; jj < 4; ++jj) {
                const float x = acc[i][jj][r];
                const int col = wn + jj * 16 + lr;
                eu[(size_t)grow * 128 + col] = x;
                bu[(size_t)grow * 128 + col] = f2bf(x * wvp[jj]);
                part[i][r] = fmaf(x, wva[jj], part[i][r]);
            }
        }
#pragma unroll
    for (int off = 1; off < 16; off <<= 1)
#pragma unroll
        for (int i = 0; i < 2; ++i)
#pragma unroll
            for (int r = 0; r < 4; ++r)
                part[i][r] += __shfl_xor(part[i][r], off, 64);
    if (t < 64) sRow[t] = 0.f;
    __syncthreads();
    if (lr == 0) {
#pragma unroll
        for (int i = 0; i < 2; ++i)
#pragma unroll
            for (int r = 0; r < 4; ++r)
                atomicAdd(&sRow[wm + i * 16 + r4 + r], part[i][r]);
    }
    __syncthreads();
    if (t < 64) g_a[a_ofs + row0 + t] = sRow[t];
}

// ---------------------------------------------------------------------------
// pair tile 64x64, 4 waves (256 threads)
// ---------------------------------------------------------------------------
__device__ __forceinline__ void pair_tile64(int which, int bb, char* cA, char* cB,
                                            const float* bias1, const float* bias2,
                                            float* out1, float* out2, int t)
{
    const int l = t & 63;
    const int col0 = (bb & 127) * 64;
    const int row0 = (bb >> 7) * 64;
    {
        const short8* gA = reinterpret_cast<const short8*>(bf_sel(which ? 2 : 0)) + (size_t)row0 * 16;
        const short8* gB = reinterpret_cast<const short8*>(bf_sel(which ? 3 : 1)) + (size_t)col0 * 16;
#pragma unroll
        for (int c = 0; c < 4; ++c) {
            const int idx = c * 256 + t;          // 16B chunk, 0..1023
            const int row = idx >> 4, sub = idx & 15;
            const int dst = row * 256 + ((sub * 16) ^ ((row & 7) << 4));
            const short8 va = gA[idx];
            const short8 vb = gB[idx];
            *(short8*)(cA + dst) = va;
            *(short8*)(cB + dst) = vb;
        }
    }
    __syncthreads();

    const int w  = t >> 6;
    const int wm = (w & 1) * 32;                  // row half
    const int wn = (w >> 1) * 32;                 // col half
    const int lr = l & 15;
    const int lkb = (l >> 4) * 16;

    f32x4 acc[2][2] = {};
#pragma unroll
    for (int kk = 0; kk < 4; ++kk) {
        const int kb = kk * 64 + lkb;
        short8 a[2], b2[2];
#pragma unroll
        for (int i = 0; i < 2; ++i) {
            const int rA = wm + i * 16 + lr;
            a[i] = *(const short8*)(cA + rA * 256 + (kb ^ ((rA & 7) << 4)));
            const int rB = wn + i * 16 + lr;
            b2[i] = *(const short8*)(cB + rB * 256 + (kb ^ ((rB & 7) << 4)));
        }
#pragma unroll
        for (int i = 0; i < 2; ++i)
#pragma unroll
            for (int j = 0; j < 2; ++j)
                acc[i][j] = __builtin_amdgcn_mfma_f32_16x16x32_bf16(a[i], b2[j], acc[i][j], 0, 0, 0);
    }

    const float bias = which ? *bias2 : *bias1;
    float* outp = which ? out2 : out1;
    const int ofsU = which ? 12288 : 0;
    const int ofsV = which ? 16384 : 4096;
    const int r4 = (l >> 4) * 4;
    float au[2][4];
#pragma unroll
    for (int i = 0; i < 2; ++i)
#pragma unroll
        for (int r = 0; r < 4; ++r)
            au[i][r] = g_a[ofsU + row0 + wm + i * 16 + r4 + r];
    float av[2];
#pragma unroll
    for (int j = 0; j < 2; ++j)
        av[j] = g_a[ofsV + col0 + wn + j * 16 + lr];

#pragma unroll
    for (int i = 0; i < 2; ++i) {
#pragma unroll
        for (int r = 0; r < 4; ++r) {
            const int grow = row0 + wm + i * 16 + r4 + r;
            float* orow = outp + (size_t)grow * M_GENES + col0 + wn;
#pragma unroll
            for (int j = 0; j < 2; ++j) {
                float x = acc[i][j][r] + au[i][r] + av[j] + bias;
                if (which == 0) x = fmaxf(x, 0.f);
                else            x = __builtin_amdgcn_rcpf(1.f + __expf(-x));
                __builtin_nontemporal_store(x, orow + j * 16 + lr);
            }
        }
    }
}

// ---------------------------------------------------------------------------
// kernels
// ---------------------------------------------------------------------------
// blocks: [0,64) gaT | [64,96) W1T | [96,112) W2T | [112,368) ub1 |
//         [368,624) ub2 | [624,632) WbT1 | [632,640) WbT2
__global__ __launch_bounds__(256) void prep_all2(const float* __restrict__ gene_act,
                                                 const float* __restrict__ W1,
                                                 const float* __restrict__ W2,
                                                 const float* __restrict__ u1,
                                                 const float* __restrict__ u2,
                                                 const float* __restrict__ Wb1,
                                                 const float* __restrict__ Wb2)
{
    const int b = blockIdx.x, t = threadIdx.x;
    if (b < 64)       transpose8(gene_act, g_gaT, b * 256 + t, 512, 256);
    else if (b < 96)  transpose8(W1, g_W1T, (b - 64) * 256 + t, 256, 256);
    else if (b < 112) transpose8(W2, g_W2T, (b - 96) * 256 + t, 256, 128);
    else if (b < 624) {
        const int which = (b >= 368);
        const int c = (b - (which ? 368 : 112)) * 256 + t;   // 0..65535
        const float* u = which ? u2 : u1;
        short* ub = which ? g_ub2 : g_ub1;
        const int row = c >> 4, sub = c & 15;
        short8 o = {0, 0, 0, 0, 0, 0, 0, 0};
        if (sub < 12) {
            const float4 x0 = *(const float4*)(u + row * 100 + sub * 8);
            const float4 x1 = *(const float4*)(u + row * 100 + sub * 8 + 4);
            o[0] = f2bf(x0.x); o[1] = f2bf(x0.y); o[2] = f2bf(x0.z); o[3] = f2bf(x0.w);
            o[4] = f2bf(x1.x); o[5] = f2bf(x1.y); o[6] = f2bf(x1.z); o[7] = f2bf(x1.w);
        } else if (sub == 12) {
            const float4 x0 = *(const float4*)(u + row * 100 + 96);
            o[0] = f2bf(x0.x); o[1] = f2bf(x0.y); o[2] = f2bf(x0.z); o[3] = f2bf(x0.w);
        }
        *(short8*)(ub + (size_t)c * 8) = o;
    } else {
        const int which = (b >= 632);
        const int c = (b - (which ? 632 : 624)) * 256 + t;   // 0..2047
        const float* Wb = which ? Wb2 : Wb1;
        short* wt = which ? g_WbT2 : g_WbT1;
        const int col = c >> 4, k0 = (c & 15) * 8;
        short8 o;
#pragma unroll
        for (int j = 0; j < 8; ++j)
            o[j] = (k0 + j < 100) ? f2bf(Wb[(size_t)(k0 + j) * 128 + col]) : (short)0;
        *(short8*)(wt + (size_t)c * 8) = o;
    }
}

// L2: blocks [0,128): stream1 MLP | [128,256): embed MFMA (both streams)
__global__ __launch_bounds__(256) void fused_s1(const float* __restrict__ v1,
                                                const float* __restrict__ wp1,
                                                const float* __restrict__ wa1,
                                                const float* __restrict__ wp2,
                                                const float* __restrict__ wa2,
                                                float* __restrict__ eu1,
                                                float* __restrict__ eu2,
                                                float* __restrict__ ev1)
{
    __shared__ __align__(16) short sMem[32768];   // 64 KB
    char* cA   = (char*)sMem;
    char* cB64 = cA + 16384;
    char* cH   = cA + 32768;
    const int b = blockIdx.x, t = threadIdx.x;
    if (b < 128) {                     // stream 1: ev1 = relu(v1@W1)@W2
        const int row0 = b * 64;
        first_layer(v1, row0, 256, 1, true, cA, cH, t);
        final_layer(cH, cB64, ev1, bf_sel(1), wa1 + 128, 4096, row0, t);
    } else {
        embed_mfma(b - 128, wp1, wa1, wp2, wa2, eu1, eu2, cA, cB64, cH, t);
    }
}

// L3: blocks [0,128): stream2 MLP | [128,6272): pair1 tiles 0..6143 -> out1
__global__ __launch_bounds__(256) void pair1_s2(const float* __restrict__ v2,
                                                const float* __restrict__ wa2,
                                                float* __restrict__ ev2,
                                                const float* __restrict__ bias1,
                                                const float* __restrict__ bias2,
                                                float* __restrict__ out1,
                                                float* __restrict__ out2)
{
    __shared__ __align__(16) short sMem[32768];   // 64 KB (MLP needs it)
    char* cA   = (char*)sMem;
    char* cB64 = cA + 16384;
    char* cH   = cA + 32768;
    const int b = blockIdx.x, t = threadIdx.x;
    if (b < 128) {                     // stream 2: ev2 = relu((v2@ga)@W1)@W2
        const int row0 = b * 64;
        first_layer(v2, row0, 512, 0, false, cA, cH, t);
        mid_layer(cH, cB64, t);
        final_layer(cH, cB64, ev2, bf_sel(3), wa2 + 128, 16384, row0, t);
    } else {
        pair_tile64(0, b - 128, cA, cA + 16384, bias1, bias2, out1, out2, t);
    }
}

// L4: remaining pair1 tiles (6144..8191) + all pair2 tiles, 32 KB LDS ->
// 5 blocks/CU = 20 waves/CU for HBM write-queue occupancy.
__global__ __launch_bounds__(256) void pair_rest(const float* __restrict__ bias1,
                                                 const float* __restrict__ bias2,
                                                 float* __restrict__ out1,
                                                 float* __restrict__ out2)
{
    __shared__ __align__(16) short sMem[16384];   // 32 KB
    const int b = blockIdx.x;
    if (b < 2048)
        pair_tile64(0, b + 6144, (char*)sMem, (char*)sMem + 16384, bias1, bias2,
                    out1, out2, threadIdx.x);
    else
        pair_tile64(1, b - 2048, (char*)sMem, (char*)sMem + 16384, bias1, bias2,
                    out1, out2, threadIdx.x);
}

// ---------------------------------------------------------------------------
extern "C" void kernel_launch(void* const* d_in, const int* in_sizes, int n_in,
                              void* d_out, int out_size, void* d_ws, size_t ws_size,
                              hipStream_t stream)
{
    const float* u1       = (const float*)d_in[0];   // [4096,100]
    const float* u2       = (const float*)d_in[1];   // [4096,100]
    const float* v1       = (const float*)d_in[2];   // [8192,256]
    const float* v2       = (const float*)d_in[3];   // [8192,512]
    const float* Wb1      = (const float*)d_in[4];   // [100,128]
    const float* Wb2      = (const float*)d_in[5];   // [100,128]
    const float* Wrna1    = (const float*)d_in[6];   // [256,256]
    const float* Wrna2    = (const float*)d_in[7];   // [256,128]
    const float* gene_act = (const float*)d_in[8];   // [512,256]
    const float* w_prod1  = (const float*)d_in[9];   // [128]
    const float* w_add1   = (const float*)d_in[10];  // [256]
    const float* w_prod2  = (const float*)d_in[11];  // [128]
    const float* w_add2   = (const float*)d_in[12];  // [256]
    const float* bias1    = (const float*)d_in[13];  // scalar
    const float* bias2    = (const float*)d_in[14];  // scalar

    float* out  = (float*)d_out;
    float* out1 = out;                                      // [4096,8192]
    float* out2 = out1 + (size_t)N_CELLS * M_GENES;         // [4096,8192]
    float* eu1  = out2 + (size_t)N_CELLS * M_GENES;         // [4096,128]
    float* ev1  = eu1 + N_CELLS * 128;                      // [8192,128]
    float* eu2  = ev1 + M_GENES * 128;                      // [4096,128]
    float* ev2  = eu2 + N_CELLS * 128;                      // [8192,128]

    // L1: transposed bf16 weights + padded bf16 u inputs + WbT
    prep_all2<<<640, 256, 0, stream>>>(gene_act, Wrna1, Wrna2, u1, u2, Wb1, Wb2);

    // L2: stream-1 MLP + both u-embeds (everything pair1 needs)
    fused_s1<<<256, 256, 0, stream>>>(v1, w_prod1, w_add1, w_prod2, w_add2,
                                      eu1, eu2, ev1);

    // L3: stream-2 MLP + first 6144 pair1 tiles (covers the s2 window)
    pair1_s2<<<6272, 256, 0, stream>>>(v2, w_add2, ev2, bias1, bias2, out1, out2);

    // L4: remaining 2048 pair1 + all 8192 pair2 tiles at 5 blocks/CU
    pair_rest<<<10240, 256, 0, stream>>>(bias1, bias2, out1, out2);
}